// Round 11
// baseline (220.399 us; speedup 1.0000x reference)
//
#include <hip/hip_runtime.h>

// SRM neuron: per-row 50-tap 'same' conv -> threshold -> refractory scan.
// B=4096 rows, T=16384.
// R10: R9 was LDS-pipe bound (~118us of b128 traffic: 23 DS ops / 256 elems).
//   K1 now uses 16 elems/lane: 17 window reads + 6 writes per 1024 elems
//   (3.8x less LDS traffic). Window reads stride 64B across lanes -> XOR
//   block swizzle (blk ^ ((blk>>3)&7)) for conflict-free b128. Outputs go
//   back to coalesced stores via cand-bitmask shuffles. Conv FMA order
//   bit-identical to validated R6-R9.
//   K0 setup (taps+athr) and K2 fixup unchanged (validated).
// Fallback: validated self-contained R7 kernel if ws too small.

#define TLEN  16384
#define NROWS 4096
#define KLEN  50
#define WPB   4       // waves per 256-thread block

// K1 geometry (16 elems/lane)
#define GRP   1024    // elems per group (64 lanes x 16)
#define NGRP  16      // groups per row
#define CHK   2       // chunks per row
#define GPC   8       // groups per chunk
#define TILEB 272     // 16B blocks per wave tile (269 used, padded)

// fixup / fallback geometry (4 elems/lane)
#define FGRP  256
#define FNGRP 64
#define TILEW 336

// d_ws layout: float[0..49] taps, float[50] athr, flags int[] at byte 256.
#define WS_FLAGS_OFF 256
#define WS_NEED (WS_FLAGS_OFF + (size_t)NROWS * CHK * sizeof(int))

typedef float f4 __attribute__((ext_vector_type(4)));

__device__ __forceinline__ float uniformf(float x) {
    return __int_as_float(__builtin_amdgcn_readfirstlane(__float_as_int(x)));
}

// XOR block swizzle: spreads 64B-strided b128 accesses across all banks.
__device__ __forceinline__ int swz(int blk) { return blk ^ ((blk >> 3) & 7); }

// compose: r[s] = then[first[s]]  (apply `first`, then `then`)
__device__ __forceinline__ int map_compose(int first, int then) {
    int r = 0;
#pragma unroll
    for (int s = 0; s < 4; ++s) {
        int a = (first >> (2 * s)) & 3;
        int b = (then >> (2 * a)) & 3;
        r |= b << (2 * s);
    }
    return r;
}

// Smallest float a with (v_reset + a/100.0f) >= v_th, via exact-predicate
// binary search over order-mapped float bits. cand == (acc >= athr) EXACTLY.
__device__ float solve_thresh(float v_reset, float v_th) {
    auto tokey = [](float f) {
        unsigned u = __float_as_uint(f);
        return (u & 0x80000000u) ? ~u : (u | 0x80000000u);
    };
    auto fromkey = [](unsigned k) {
        unsigned u = (k & 0x80000000u) ? (k & 0x7FFFFFFFu) : ~k;
        return __uint_as_float(u);
    };
    const float maxf = 3.402823466e38f;
    unsigned lo = tokey(-maxf), hi = tokey(maxf);
    if (!((v_reset + maxf / 100.0f) >= v_th))
        return __uint_as_float(0x7F800000u);  // pred never true -> +inf
    while (lo < hi) {
        unsigned mid = lo + ((hi - lo) >> 1);
        float a = fromkey(mid);
        if ((v_reset + a / 100.0f) >= v_th) hi = mid;
        else lo = mid + 1;
    }
    return fromkey(lo);
}

// ---------------- K0: taps + exact threshold -> d_ws ----------------
__global__ __launch_bounds__(64)
void setup_kernel(const float* __restrict__ p_tau_m,
                  const float* __restrict__ p_tau_s,
                  const float* __restrict__ p_v_th,
                  const float* __restrict__ p_v_reset,
                  float* __restrict__ wsf)
{
    const int lane = threadIdx.x & 63;
    const float tau_m = p_tau_m[0];
    const float tau_s = p_tau_s[0];

    float ft = (float)lane;
    float v = (lane < KLEN) ? (expf(-ft / tau_m) - expf(-ft / tau_s)) : 0.0f;

    // Reference-ordered sequential sum t = 0..49 (bit-identical order).
    float ksum = 0.0f;
    for (int t = 0; t < KLEN; ++t)
        ksum += __shfl(v, t, 64);
    const float kden = ksum + 1e-10f;
    const float kt = v / kden;

    if (lane < KLEN) wsf[lane] = kt;
    if (lane == 0)   wsf[KLEN] = solve_thresh(p_v_reset[0], p_v_th[0]);
}

// ---------------- K1: conv (E=16) -> spikes(=cand) + per-chunk flags ----------------
__global__ __launch_bounds__(256)
void conv_kernel(const float* __restrict__ I,
                 const float* __restrict__ wsf,   // taps + athr (uniform loads)
                 float* __restrict__ out,
                 int* __restrict__ flags)
{
    __shared__ __align__(16) float tile[WPB][TILEB * 4];

    const int lane  = threadIdx.x & 63;
    const int wid   = threadIdx.x >> 6;
    const int w     = blockIdx.x * WPB + wid;    // 0 .. NROWS*CHK-1
    const int row   = w >> 1;
    const int chunk = w & 1;

    float kt[KLEN];
#pragma unroll
    for (int t = 0; t < KLEN; ++t) kt[t] = wsf[t];
    const float athr = wsf[KLEN];

    const float* Irow = I + (size_t)row * TLEN;
    float* Orow = out + (size_t)row * TLEN;

    char* tb_ = (char*)&tile[wid][0];

    // Precomputed swizzled byte offsets.
    // Tile linear layout (float units): [0..27] halo-left (e_rel -28..-1),
    // [28..1051] main (e_rel 0..1023), [1052..1075] halo-right (1024..1047).
    int rdoff[17];
#pragma unroll
    for (int i = 0; i < 17; ++i) rdoff[i] = 16 * swz(4 * lane + i);
    int wroff[4];
#pragma unroll
    for (int j = 0; j < 4; ++j) wroff[j] = 16 * swz(7 + lane + 64 * j);
    const int hloff = 16 * swz(lane & 7);              // lanes 0..6
    const int hroff = 16 * swz(263 + ((lane - 56) & 7)); // lanes 56..61

    int rowflag = 0;

    for (int g = 0; g < GPC; ++g) {
        const int gi   = chunk * GPC + g;
        const int base = gi * GRP;

        // ---- stage main 1024 elems (coalesced loads, swizzled LDS writes) ----
        f4 mv0 = *(const f4*)(Irow + base + 4 * lane);
        f4 mv1 = *(const f4*)(Irow + base + 4 * lane + 256);
        f4 mv2 = *(const f4*)(Irow + base + 4 * lane + 512);
        f4 mv3 = *(const f4*)(Irow + base + 4 * lane + 768);
        *(f4*)(tb_ + wroff[0]) = mv0;
        *(f4*)(tb_ + wroff[1]) = mv1;
        *(f4*)(tb_ + wroff[2]) = mv2;
        *(f4*)(tb_ + wroff[3]) = mv3;
        // halo-left: 7 blocks, e_rel -28..-1 (zeros at row start)
        if (lane < 7) {
            f4 h = (f4){0.0f, 0.0f, 0.0f, 0.0f};
            if (gi > 0) h = *(const f4*)(Irow + base - 28 + 4 * lane);
            *(f4*)(tb_ + hloff) = h;
        }
        // halo-right: 6 blocks, e_rel 1024..1047 (zeros past row end)
        if (lane >= 56 && lane < 62) {
            f4 h = (f4){0.0f, 0.0f, 0.0f, 0.0f};
            if (gi < NGRP - 1) h = *(const f4*)(Irow + base + GRP + 4 * (lane - 56));
            *(f4*)(tb_ + hroff) = h;
        }

        // ---- window read: tile floats 16l+3 .. 16l+67 (17 blocks) ----
        f4 wv[17];
#pragma unroll
        for (int i = 0; i < 17; ++i)
            wv[i] = *(const f4*)(tb_ + rdoff[i]);
#define WIN(m) (wv[(m) >> 2][(m) & 3])

        // ---- convolution: per output k, jj descends 49..0 (identical
        //      order/operands to validated R6-R9) ----
        float acc[16];
#pragma unroll
        for (int k = 0; k < 16; ++k) acc[k] = 0.0f;
#pragma unroll
        for (int o = -25; o <= 39; ++o) {
            const float wx = WIN(o + 28);
#pragma unroll
            for (int k = 0; k < 16; ++k) {
                const int jj = k + 24 - o;
                if (jj >= 0 && jj < KLEN)
                    acc[k] = fmaf(kt[jj], wx, acc[k]);
            }
        }
#undef WIN

        // ---- candidate bitmask (bit k = output 16*lane + k) ----
        int m16 = 0;
#pragma unroll
        for (int k = 0; k < 16; ++k)
            m16 |= (acc[k] >= athr) ? (1 << k) : 0;
        if (base + 16 * lane == 0) m16 &= ~1;   // spikes[0] forced 0
        rowflag |= m16;

        // ---- transpose to coalesced stores via shuffles ----
        // output float p = base + 4*lane + 256*j + c comes from
        // src lane (lane>>2)+16j, bit 4*(lane&3)+c.
        const int sh = 4 * (lane & 3);
#pragma unroll
        for (int j = 0; j < 4; ++j) {
            const int bits = __shfl(m16, (lane >> 2) + 16 * j, 64);
            f4 o0;
            o0.x = ((bits >> (sh + 0)) & 1) ? 1.0f : 0.0f;
            o0.y = ((bits >> (sh + 1)) & 1) ? 1.0f : 0.0f;
            o0.z = ((bits >> (sh + 2)) & 1) ? 1.0f : 0.0f;
            o0.w = ((bits >> (sh + 3)) & 1) ? 1.0f : 0.0f;
            __builtin_nontemporal_store(o0, (f4*)(Orow + base + 4 * lane + 256 * j));
        }
    }

    // Deterministic flag write for every chunk (0 or 1).
    const unsigned long long anyb = __ballot(rowflag != 0);
    if (lane == 0) flags[w] = (anyb != 0ULL) ? 1 : 0;
}

// ---------------- K2: repair flagged rows with exact refractory scan ----------------
__global__ __launch_bounds__(256)
void fixup_kernel(const int* __restrict__ flags,
                  float* __restrict__ out)
{
    const int lane = threadIdx.x & 63;
    const int wid  = threadIdx.x >> 6;
    const int row  = blockIdx.x * WPB + wid;

    if ((flags[2 * row] | flags[2 * row + 1]) == 0) return;  // wave-uniform

    float* Orow = out + (size_t)row * TLEN;
    int r0 = 0;

    for (int g = 0; g < FNGRP; ++g) {
        f4 o = *(const f4*)(Orow + g * FGRP + 4 * lane);
        int cand[4];
        cand[0] = (o.x != 0.0f);
        cand[1] = (o.y != 0.0f);
        cand[2] = (o.z != 0.0f);
        cand[3] = (o.w != 0.0f);

        const int cm = cand[0] | cand[1] | cand[2] | cand[3];
        const unsigned long long anyc = __ballot(cm != 0);
        if (anyc == 0ULL) { r0 = 0; continue; }   // zeros already correct

        int s0 = 0, s1 = 1, s2 = 2, s3 = 3;
#pragma unroll
        for (int k = 0; k < 4; ++k) {
            const int c3 = cand[k] ? 3 : 0;
            s0 = (s0 > 0) ? (s0 - 1) : c3;
            s1 = (s1 > 0) ? (s1 - 1) : c3;
            s2 = (s2 > 0) ? (s2 - 1) : c3;
            s3 = (s3 > 0) ? (s3 - 1) : c3;
        }
        int P = s0 | (s1 << 2) | (s2 << 4) | (s3 << 6);

#pragma unroll
        for (int d = 1; d < 64; d <<= 1) {
            const int prev = __shfl_up(P, d, 64);
            const int comp = map_compose(prev, P);
            P = (lane >= d) ? comp : P;
        }
        const int Pprev = __shfl_up(P, 1, 64);
        const int sin0  = (lane == 0) ? r0 : ((Pprev >> (2 * r0)) & 3);
        const int Pfull = __shfl(P, 63, 64);
        r0 = (Pfull >> (2 * r0)) & 3;

        int s = sin0;
        float sp[4];
#pragma unroll
        for (int k = 0; k < 4; ++k) {
            const int spike = (s == 0) & cand[k];
            sp[k] = spike ? 1.0f : 0.0f;
            s = (s > 0) ? (s - 1) : (cand[k] ? 3 : 0);
        }
        f4 o0; o0.x = sp[0]; o0.y = sp[1]; o0.z = sp[2]; o0.w = sp[3];
        *(f4*)(Orow + g * FGRP + 4 * lane) = o0;
    }
}

// ---------------- Fallback: validated R7 single kernel ----------------
__global__ __launch_bounds__(256)
void srm_kernel(const float* __restrict__ I,
                const float* __restrict__ p_tau_m,
                const float* __restrict__ p_tau_s,
                const float* __restrict__ p_v_th,
                const float* __restrict__ p_v_reset,
                float* __restrict__ out)
{
    __shared__ __align__(16) float tile[WPB][2][TILEW];

    const int lane = threadIdx.x & 63;
    const int wid  = threadIdx.x >> 6;
    const int row  = blockIdx.x * WPB + wid;

    const float tau_m   = p_tau_m[0];
    const float tau_s   = p_tau_s[0];
    const float v_th    = p_v_th[0];
    const float v_reset = p_v_reset[0];

    float ku[KLEN];
    float ksum = 0.0f;
#pragma unroll
    for (int t = 0; t < KLEN; ++t) {
        float ft = (float)t;
        float v = expf(-ft / tau_m) - expf(-ft / tau_s);
        ksum += v;
        ku[t] = uniformf(v);
    }
    const float kden = uniformf(ksum + 1e-10f);
    float kt[KLEN];
#pragma unroll
    for (int t = 0; t < KLEN; ++t) kt[t] = uniformf(ku[t] / kden);

    const float athr = uniformf(solve_thresh(v_reset, v_th));

    const float* Irow = I + (size_t)row * TLEN;
    float* Orow = out + (size_t)row * TLEN;

    float Cv[4], Nv[4], Lv[4];
    {
        f4 a = *(const f4*)(Irow + 0 * FGRP + 4 * lane);
        Cv[0] = a.x; Cv[1] = a.y; Cv[2] = a.z; Cv[3] = a.w;
        f4 c = *(const f4*)(Irow + 1 * FGRP + 4 * lane);
        Nv[0] = c.x; Nv[1] = c.y; Nv[2] = c.z; Nv[3] = c.w;
    }

    if (lane < 8) {
        f4 z = (f4){0.0f, 0.0f, 0.0f, 0.0f};
        *(f4*)&tile[wid][0][4 * lane] = z;
    }
    {
        f4 c; c.x = Cv[0]; c.y = Cv[1]; c.z = Cv[2]; c.w = Cv[3];
        *(f4*)&tile[wid][0][32 + 4 * lane] = c;
    }

    int r0 = 0;

    for (int g = 0; g < FNGRP; ++g) {
        const int cur = g & 1;
        const int nxt = cur ^ 1;

        if (g + 2 < FNGRP) {
            f4 a = *(const f4*)(Irow + (size_t)(g + 2) * FGRP + 4 * lane);
            Lv[0] = a.x; Lv[1] = a.y; Lv[2] = a.z; Lv[3] = a.w;
        } else {
            Lv[0] = Lv[1] = Lv[2] = Lv[3] = 0.0f;
        }

        f4 nv; nv.x = Nv[0]; nv.y = Nv[1]; nv.z = Nv[2]; nv.w = Nv[3];
        if (lane < 8)
            *(f4*)&tile[wid][cur][288 + 4 * lane] = nv;
        *(f4*)&tile[wid][nxt][32 + 4 * lane] = nv;
        if (lane >= 56) {
            f4 cv; cv.x = Cv[0]; cv.y = Cv[1]; cv.z = Cv[2]; cv.w = Cv[3];
            *(f4*)&tile[wid][nxt][4 * (lane - 56)] = cv;
        }

        f4 wv[15];
#pragma unroll
        for (int i = 0; i < 15; ++i)
            wv[i] = *(const f4*)&tile[wid][cur][4 * lane + 4 + 4 * i];
#define WIN(m) (wv[(m) >> 2][(m) & 3])

        float acc[4];
        acc[0] = acc[1] = acc[2] = acc[3] = 0.0f;
#pragma unroll
        for (int o = -25; o <= 27; ++o) {
            const float w = WIN(o + 28);
#pragma unroll
            for (int k = 0; k < 4; ++k) {
                const int jj = k + 24 - o;
                if (jj >= 0 && jj < KLEN)
                    acc[k] = fmaf(kt[jj], w, acc[k]);
            }
        }
#undef WIN

        const int tb = g * FGRP + 4 * lane;
        int cand[4];
#pragma unroll
        for (int k = 0; k < 4; ++k)
            cand[k] = (acc[k] >= athr) ? 1 : 0;
        cand[0] &= (tb != 0);

        const int cm = cand[0] | cand[1] | cand[2] | cand[3];
        const unsigned long long anyc = __ballot(cm != 0);

        f4 o0;
        if (anyc == 0ULL) {
            o0 = (f4){0.0f, 0.0f, 0.0f, 0.0f};
            r0 = 0;
        } else {
            int s0 = 0, s1 = 1, s2 = 2, s3 = 3;
#pragma unroll
            for (int k = 0; k < 4; ++k) {
                const int c3 = cand[k] ? 3 : 0;
                s0 = (s0 > 0) ? (s0 - 1) : c3;
                s1 = (s1 > 0) ? (s1 - 1) : c3;
                s2 = (s2 > 0) ? (s2 - 1) : c3;
                s3 = (s3 > 0) ? (s3 - 1) : c3;
            }
            int P = s0 | (s1 << 2) | (s2 << 4) | (s3 << 6);
#pragma unroll
            for (int d = 1; d < 64; d <<= 1) {
                const int prev = __shfl_up(P, d, 64);
                const int comp = map_compose(prev, P);
                P = (lane >= d) ? comp : P;
            }
            const int Pprev = __shfl_up(P, 1, 64);
            const int sin0  = (lane == 0) ? r0 : ((Pprev >> (2 * r0)) & 3);
            const int Pfull = __shfl(P, 63, 64);
            r0 = (Pfull >> (2 * r0)) & 3;

            int s = sin0;
            float sp[4];
#pragma unroll
            for (int k = 0; k < 4; ++k) {
                const int spike = (s == 0) & cand[k];
                sp[k] = spike ? 1.0f : 0.0f;
                s = (s > 0) ? (s - 1) : (cand[k] ? 3 : 0);
            }
            o0.x = sp[0]; o0.y = sp[1]; o0.z = sp[2]; o0.w = sp[3];
        }

        __builtin_nontemporal_store(o0, (f4*)(Orow + tb));

#pragma unroll
        for (int j = 0; j < 4; ++j) { Cv[j] = Nv[j]; Nv[j] = Lv[j]; }
    }
}

extern "C" void kernel_launch(void* const* d_in, const int* in_sizes, int n_in,
                              void* d_out, int out_size, void* d_ws, size_t ws_size,
                              hipStream_t stream) {
    const float* I       = (const float*)d_in[0];
    const float* tau_m   = (const float*)d_in[1];
    const float* tau_s   = (const float*)d_in[2];
    const float* v_th    = (const float*)d_in[3];
    const float* v_reset = (const float*)d_in[4];
    float* out = (float*)d_out;

    if (ws_size >= WS_NEED) {
        float* wsf  = (float*)d_ws;
        int* flags  = (int*)((char*)d_ws + WS_FLAGS_OFF);
        setup_kernel<<<dim3(1), dim3(64), 0, stream>>>(
            tau_m, tau_s, v_th, v_reset, wsf);
        conv_kernel<<<dim3(NROWS * CHK / WPB), dim3(256), 0, stream>>>(
            I, wsf, out, flags);
        fixup_kernel<<<dim3(NROWS / WPB), dim3(256), 0, stream>>>(flags, out);
    } else {
        srm_kernel<<<dim3(NROWS / WPB), dim3(256), 0, stream>>>(
            I, tau_m, tau_s, v_th, v_reset, out);
    }
}

// Round 12
// 161.229 us; speedup vs baseline: 1.3670x; 1.3670x over previous
//
#include <hip/hip_runtime.h>

// SRM neuron: per-row 50-tap 'same' conv -> threshold -> refractory scan.
// B=4096 rows, T=16384.
// R11: replace the 50-FMA/elem direct conv (VALU-issue bound at ~128us busy
//      across R7/R9/R10) with the exact geometric recurrence
//        y[t] = A*y[t-1] + x[t] - A^50*x[t-50]   (A = e^(-1/tau))
//      for both exponentials, in f64 (~4 f64 FMA/elem). Cross-lane carry via
//      affine-map Hillis-Steele scan (uniform A^(4d) factors). 'same' shift
//      (+24) via output offset. spikes := cand + flags; validated fixup
//      kernel repairs refractory overlaps on flagged rows.
// Fallback: validated self-contained R7 kernel if ws too small.

#define TLEN  16384
#define NROWS 4096
#define KLEN  50
#define WPB   4       // waves per 256-thread block
#define CHK   2       // chunks per row
#define SH    24      // 'same' conv center shift ((KLEN-1)//2)

// fixup / fallback geometry
#define FGRP  256
#define FNGRP 64
#define TILEW 336

#define WS_NEED ((size_t)NROWS * CHK * sizeof(int))

typedef float f4 __attribute__((ext_vector_type(4)));

__device__ __forceinline__ float uniformf(float x) {
    return __int_as_float(__builtin_amdgcn_readfirstlane(__float_as_int(x)));
}

__device__ __forceinline__ double uniformd(double x) {
    long long i = __double_as_longlong(x);
    int lo = __builtin_amdgcn_readfirstlane((int)(i & 0xffffffffLL));
    int hi = __builtin_amdgcn_readfirstlane((int)(i >> 32));
    return __longlong_as_double(((long long)hi << 32) | (unsigned int)lo);
}

// compose: r[s] = then[first[s]]  (apply `first`, then `then`)
__device__ __forceinline__ int map_compose(int first, int then) {
    int r = 0;
#pragma unroll
    for (int s = 0; s < 4; ++s) {
        int a = (first >> (2 * s)) & 3;
        int b = (then >> (2 * a)) & 3;
        r |= b << (2 * s);
    }
    return r;
}

// Smallest float a with (v_reset + a/100.0f) >= v_th, via exact-predicate
// binary search over order-mapped float bits. cand == (acc >= athr) EXACTLY.
__device__ float solve_thresh(float v_reset, float v_th) {
    auto tokey = [](float f) {
        unsigned u = __float_as_uint(f);
        return (u & 0x80000000u) ? ~u : (u | 0x80000000u);
    };
    auto fromkey = [](unsigned k) {
        unsigned u = (k & 0x80000000u) ? (k & 0x7FFFFFFFu) : ~k;
        return __uint_as_float(u);
    };
    const float maxf = 3.402823466e38f;
    unsigned lo = tokey(-maxf), hi = tokey(maxf);
    if (!((v_reset + maxf / 100.0f) >= v_th))
        return __uint_as_float(0x7F800000u);  // pred never true -> +inf
    while (lo < hi) {
        unsigned mid = lo + ((hi - lo) >> 1);
        float a = fromkey(mid);
        if ((v_reset + a / 100.0f) >= v_th) hi = mid;
        else lo = mid + 1;
    }
    return fromkey(lo);
}

// ---------------- K1: recurrence conv -> spikes(=cand) + flags ----------------
__global__ __launch_bounds__(256)
void conv_kernel(const float* __restrict__ I,
                 const float* __restrict__ p_tau_m,
                 const float* __restrict__ p_tau_s,
                 const float* __restrict__ p_v_th,
                 const float* __restrict__ p_v_reset,
                 float* __restrict__ out,
                 int* __restrict__ flags)
{
    const int lane  = threadIdx.x & 63;
    const int wid   = threadIdx.x >> 6;
    const int w     = blockIdx.x * WPB + wid;    // 0 .. NROWS*CHK-1
    const int row   = w >> 1;
    const int chunk = w & 1;

    const double tm = (double)p_tau_m[0];
    const double ts = (double)p_tau_s[0];

    // Wave-uniform f64 constants (pinned to SGPRs via readfirstlane).
    const double Ad  = uniformd(exp(-1.0 / tm));
    const double Bd  = uniformd(exp(-1.0 / ts));
    const double A50 = uniformd(exp(-50.0 / tm));
    const double B50 = uniformd(exp(-50.0 / ts));
    const double A2 = uniformd(Ad * Ad), A3 = uniformd(A2 * Ad), A4 = uniformd(A2 * A2);
    const double B2 = uniformd(Bd * Bd), B3 = uniformd(B2 * Bd), B4 = uniformd(B2 * B2);
    double sa[6], sb[6];
    sa[0] = A4; sb[0] = B4;
#pragma unroll
    for (int i = 1; i < 6; ++i) {
        sa[i] = uniformd(sa[i - 1] * sa[i - 1]);
        sb[i] = uniformd(sb[i - 1] * sb[i - 1]);
    }
    const double A256 = uniformd(sa[5] * sa[5]);
    const double B256 = uniformd(sb[5] * sb[5]);

    // Unnormalized-tap sum S = sum (A^t - B^t), t<50 ; threshold on the
    // UNNORMALIZED window sum: cand <=> (ya - yb) >= athr * (S + 1e-10).
    const double S = (1.0 - A50) / (1.0 - Ad) - (1.0 - B50) / (1.0 - Bd);
    const float athr = uniformf(solve_thresh(p_v_reset[0], p_v_th[0]));
    const double athrS = uniformd((double)athr * (S + 1e-10));

    // Per-lane decay powers.
    const double pAl  = exp(-(double)lane / tm);     // A^lane (warm-up)
    const double pBl  = exp(-(double)lane / ts);
    double t0 = pAl * pAl;  const double pA4l = t0 * t0;   // A^(4*lane)
    double t1 = pBl * pBl;  const double pB4l = t1 * t1;

    const float* Irow = I + (size_t)row * TLEN;
    float* Orow = out + (size_t)row * TLEN;

    // y-position base: chunk c produces outputs [8192c, 8192c+8192) from
    // window-end positions [8192c+SH, ...). Chunk 0 runs 33 groups from 0;
    // chunk 1 runs 32 groups from 8216 (= 8192+SH).
    const int ybase = chunk ? (8192 + SH) : 0;
    const int ng    = chunk ? 32 : 33;
    const int obeg  = chunk * 8192;

    // Warm-up for chunk 1: y state = window ending at position ybase-1.
    double yga = 0.0, ygb = 0.0;
    if (chunk == 1) {
        float xw = (lane < KLEN) ? Irow[(ybase - 1) - lane] : 0.0f;
        double wa = pAl * (double)xw;
        double wb = pBl * (double)xw;
#pragma unroll
        for (int d = 1; d < 64; d <<= 1) {
            wa += __shfl_xor(wa, d, 64);
            wb += __shfl_xor(wb, d, 64);
        }
        yga = wa; ygb = wb;
    }

    int rowflag = 0;

    for (int g = 0; g < ng; ++g) {
        const int pos0 = ybase + g * 256 + 4 * lane;   // first y-position

        // ---- load x[pos0..pos0+3] (0 past row end; clamp address) ----
        const bool xvalid = (pos0 <= TLEN - 4);
        f4 xv = *(const f4*)(Irow + (xvalid ? pos0 : TLEN - 4));
        if (!xvalid) xv = (f4){0.0f, 0.0f, 0.0f, 0.0f};

        // ---- load lag x[pos0-50 ..] ----
        float lg[4];
        if (chunk == 0 && g == 0) {
            // pos < 50 -> x[neg] = 0 (per-component scalar path, once)
#pragma unroll
            for (int k = 0; k < 4; ++k) {
                const int t = pos0 + k;
                lg[k] = (t >= KLEN) ? Irow[t - KLEN] : 0.0f;
            }
        } else {
            f4 lv = *(const f4*)(Irow + pos0 - KLEN);
            lg[0] = lv.x; lg[1] = lv.y; lg[2] = lv.z; lg[3] = lv.w;
        }

        // ---- local recurrence pass (y_in = 0) ----
        const double x0 = (double)xv.x, x1 = (double)xv.y,
                     x2 = (double)xv.z, x3 = (double)xv.w;
        const double l0 = (double)lg[0], l1 = (double)lg[1],
                     l2 = (double)lg[2], l3 = (double)lg[3];

        double pa[4], pb[4];
        pa[0] = fma(-A50, l0, x0);
        pa[1] = fma(Ad, pa[0], fma(-A50, l1, x1));
        pa[2] = fma(Ad, pa[1], fma(-A50, l2, x2));
        pa[3] = fma(Ad, pa[2], fma(-A50, l3, x3));
        pb[0] = fma(-B50, l0, x0);
        pb[1] = fma(Bd, pb[0], fma(-B50, l1, x1));
        pb[2] = fma(Bd, pb[1], fma(-B50, l2, x2));
        pb[3] = fma(Bd, pb[2], fma(-B50, l3, x3));

        // ---- affine-map scan across lanes: T_l(y) = A^4 y + gamma ----
        double ga = pa[3], gb = pb[3];
#pragma unroll
        for (int i = 0; i < 6; ++i) {
            const int d = 1 << i;
            const double gap = __shfl_up(ga, d, 64);
            const double gbp = __shfl_up(gb, d, 64);
            ga = (lane >= d) ? fma(sa[i], gap, ga) : ga;
            gb = (lane >= d) ? fma(sb[i], gbp, gb) : gb;
        }
        // exclusive prefix -> incoming state for this lane
        double gax = __shfl_up(ga, 1, 64);
        double gbx = __shfl_up(gb, 1, 64);
        gax = (lane == 0) ? 0.0 : gax;
        gbx = (lane == 0) ? 0.0 : gbx;
        const double yina = fma(pA4l, yga, gax);
        const double yinb = fma(pB4l, ygb, gbx);
        // group carry (from lane 63's inclusive transform)
        const double g63a = __shfl(ga, 63, 64);
        const double g63b = __shfl(gb, 63, 64);
        yga = fma(A256, yga, g63a);
        ygb = fma(B256, ygb, g63b);

        // ---- finalize, threshold ----
        int cand[4];
        cand[0] = (fma(Ad, yina, pa[0]) - fma(Bd, yinb, pb[0])) >= athrS;
        cand[1] = (fma(A2, yina, pa[1]) - fma(B2, yinb, pb[1])) >= athrS;
        cand[2] = (fma(A3, yina, pa[2]) - fma(B3, yinb, pb[2])) >= athrS;
        cand[3] = (fma(A4, yina, pa[3]) - fma(B4, yinb, pb[3])) >= athrS;

        // ---- store at shifted output position ----
        const int op0 = pos0 - SH;
        const bool store_ok = (op0 >= obeg) && (op0 < obeg + 8192);
        if (op0 == 0) cand[0] = 0;   // spikes[0] forced 0
        if (store_ok) {
            rowflag |= cand[0] | cand[1] | cand[2] | cand[3];
            f4 o0;
            o0.x = cand[0] ? 1.0f : 0.0f;
            o0.y = cand[1] ? 1.0f : 0.0f;
            o0.z = cand[2] ? 1.0f : 0.0f;
            o0.w = cand[3] ? 1.0f : 0.0f;
            __builtin_nontemporal_store(o0, (f4*)(Orow + op0));
        }
    }

    const unsigned long long anyb = __ballot(rowflag != 0);
    if (lane == 0) flags[w] = (anyb != 0ULL) ? 1 : 0;
}

// ---------------- K2: repair flagged rows with exact refractory scan ----------------
__global__ __launch_bounds__(256)
void fixup_kernel(const int* __restrict__ flags,
                  float* __restrict__ out)
{
    const int lane = threadIdx.x & 63;
    const int wid  = threadIdx.x >> 6;
    const int row  = blockIdx.x * WPB + wid;

    if ((flags[2 * row] | flags[2 * row + 1]) == 0) return;  // wave-uniform

    float* Orow = out + (size_t)row * TLEN;
    int r0 = 0;

    for (int g = 0; g < FNGRP; ++g) {
        f4 o = *(const f4*)(Orow + g * FGRP + 4 * lane);
        int cand[4];
        cand[0] = (o.x != 0.0f);
        cand[1] = (o.y != 0.0f);
        cand[2] = (o.z != 0.0f);
        cand[3] = (o.w != 0.0f);

        const int cm = cand[0] | cand[1] | cand[2] | cand[3];
        const unsigned long long anyc = __ballot(cm != 0);
        if (anyc == 0ULL) { r0 = 0; continue; }   // zeros already correct

        int s0 = 0, s1 = 1, s2 = 2, s3 = 3;
#pragma unroll
        for (int k = 0; k < 4; ++k) {
            const int c3 = cand[k] ? 3 : 0;
            s0 = (s0 > 0) ? (s0 - 1) : c3;
            s1 = (s1 > 0) ? (s1 - 1) : c3;
            s2 = (s2 > 0) ? (s2 - 1) : c3;
            s3 = (s3 > 0) ? (s3 - 1) : c3;
        }
        int P = s0 | (s1 << 2) | (s2 << 4) | (s3 << 6);

#pragma unroll
        for (int d = 1; d < 64; d <<= 1) {
            const int prev = __shfl_up(P, d, 64);
            const int comp = map_compose(prev, P);
            P = (lane >= d) ? comp : P;
        }
        const int Pprev = __shfl_up(P, 1, 64);
        const int sin0  = (lane == 0) ? r0 : ((Pprev >> (2 * r0)) & 3);
        const int Pfull = __shfl(P, 63, 64);
        r0 = (Pfull >> (2 * r0)) & 3;

        int s = sin0;
        float sp[4];
#pragma unroll
        for (int k = 0; k < 4; ++k) {
            const int spike = (s == 0) & cand[k];
            sp[k] = spike ? 1.0f : 0.0f;
            s = (s > 0) ? (s - 1) : (cand[k] ? 3 : 0);
        }
        f4 o0; o0.x = sp[0]; o0.y = sp[1]; o0.z = sp[2]; o0.w = sp[3];
        *(f4*)(Orow + g * FGRP + 4 * lane) = o0;
    }
}

// ---------------- Fallback: validated R7 single kernel ----------------
__global__ __launch_bounds__(256)
void srm_kernel(const float* __restrict__ I,
                const float* __restrict__ p_tau_m,
                const float* __restrict__ p_tau_s,
                const float* __restrict__ p_v_th,
                const float* __restrict__ p_v_reset,
                float* __restrict__ out)
{
    __shared__ __align__(16) float tile[WPB][2][TILEW];

    const int lane = threadIdx.x & 63;
    const int wid  = threadIdx.x >> 6;
    const int row  = blockIdx.x * WPB + wid;

    const float tau_m   = p_tau_m[0];
    const float tau_s   = p_tau_s[0];
    const float v_th    = p_v_th[0];
    const float v_reset = p_v_reset[0];

    float ku[KLEN];
    float ksum = 0.0f;
#pragma unroll
    for (int t = 0; t < KLEN; ++t) {
        float ft = (float)t;
        float v = expf(-ft / tau_m) - expf(-ft / tau_s);
        ksum += v;
        ku[t] = uniformf(v);
    }
    const float kden = uniformf(ksum + 1e-10f);
    float kt[KLEN];
#pragma unroll
    for (int t = 0; t < KLEN; ++t) kt[t] = uniformf(ku[t] / kden);

    const float athr = uniformf(solve_thresh(v_reset, v_th));

    const float* Irow = I + (size_t)row * TLEN;
    float* Orow = out + (size_t)row * TLEN;

    float Cv[4], Nv[4], Lv[4];
    {
        f4 a = *(const f4*)(Irow + 0 * FGRP + 4 * lane);
        Cv[0] = a.x; Cv[1] = a.y; Cv[2] = a.z; Cv[3] = a.w;
        f4 c = *(const f4*)(Irow + 1 * FGRP + 4 * lane);
        Nv[0] = c.x; Nv[1] = c.y; Nv[2] = c.z; Nv[3] = c.w;
    }

    if (lane < 8) {
        f4 z = (f4){0.0f, 0.0f, 0.0f, 0.0f};
        *(f4*)&tile[wid][0][4 * lane] = z;
    }
    {
        f4 c; c.x = Cv[0]; c.y = Cv[1]; c.z = Cv[2]; c.w = Cv[3];
        *(f4*)&tile[wid][0][32 + 4 * lane] = c;
    }

    int r0 = 0;

    for (int g = 0; g < FNGRP; ++g) {
        const int cur = g & 1;
        const int nxt = cur ^ 1;

        if (g + 2 < FNGRP) {
            f4 a = *(const f4*)(Irow + (size_t)(g + 2) * FGRP + 4 * lane);
            Lv[0] = a.x; Lv[1] = a.y; Lv[2] = a.z; Lv[3] = a.w;
        } else {
            Lv[0] = Lv[1] = Lv[2] = Lv[3] = 0.0f;
        }

        f4 nv; nv.x = Nv[0]; nv.y = Nv[1]; nv.z = Nv[2]; nv.w = Nv[3];
        if (lane < 8)
            *(f4*)&tile[wid][cur][288 + 4 * lane] = nv;
        *(f4*)&tile[wid][nxt][32 + 4 * lane] = nv;
        if (lane >= 56) {
            f4 cv; cv.x = Cv[0]; cv.y = Cv[1]; cv.z = Cv[2]; cv.w = Cv[3];
            *(f4*)&tile[wid][nxt][4 * (lane - 56)] = cv;
        }

        f4 wv[15];
#pragma unroll
        for (int i = 0; i < 15; ++i)
            wv[i] = *(const f4*)&tile[wid][cur][4 * lane + 4 + 4 * i];
#define WIN(m) (wv[(m) >> 2][(m) & 3])

        float acc[4];
        acc[0] = acc[1] = acc[2] = acc[3] = 0.0f;
#pragma unroll
        for (int o = -25; o <= 27; ++o) {
            const float w = WIN(o + 28);
#pragma unroll
            for (int k = 0; k < 4; ++k) {
                const int jj = k + 24 - o;
                if (jj >= 0 && jj < KLEN)
                    acc[k] = fmaf(kt[jj], w, acc[k]);
            }
        }
#undef WIN

        const int tb = g * FGRP + 4 * lane;
        int cand[4];
#pragma unroll
        for (int k = 0; k < 4; ++k)
            cand[k] = (acc[k] >= athr) ? 1 : 0;
        cand[0] &= (tb != 0);

        const int cm = cand[0] | cand[1] | cand[2] | cand[3];
        const unsigned long long anyc = __ballot(cm != 0);

        f4 o0;
        if (anyc == 0ULL) {
            o0 = (f4){0.0f, 0.0f, 0.0f, 0.0f};
            r0 = 0;
        } else {
            int s0 = 0, s1 = 1, s2 = 2, s3 = 3;
#pragma unroll
            for (int k = 0; k < 4; ++k) {
                const int c3 = cand[k] ? 3 : 0;
                s0 = (s0 > 0) ? (s0 - 1) : c3;
                s1 = (s1 > 0) ? (s1 - 1) : c3;
                s2 = (s2 > 0) ? (s2 - 1) : c3;
                s3 = (s3 > 0) ? (s3 - 1) : c3;
            }
            int P = s0 | (s1 << 2) | (s2 << 4) | (s3 << 6);
#pragma unroll
            for (int d = 1; d < 64; d <<= 1) {
                const int prev = __shfl_up(P, d, 64);
                const int comp = map_compose(prev, P);
                P = (lane >= d) ? comp : P;
            }
            const int Pprev = __shfl_up(P, 1, 64);
            const int sin0  = (lane == 0) ? r0 : ((Pprev >> (2 * r0)) & 3);
            const int Pfull = __shfl(P, 63, 64);
            r0 = (Pfull >> (2 * r0)) & 3;

            int s = sin0;
            float sp[4];
#pragma unroll
            for (int k = 0; k < 4; ++k) {
                const int spike = (s == 0) & cand[k];
                sp[k] = spike ? 1.0f : 0.0f;
                s = (s > 0) ? (s - 1) : (cand[k] ? 3 : 0);
            }
            o0.x = sp[0]; o0.y = sp[1]; o0.z = sp[2]; o0.w = sp[3];
        }

        __builtin_nontemporal_store(o0, (f4*)(Orow + tb));

#pragma unroll
        for (int j = 0; j < 4; ++j) { Cv[j] = Nv[j]; Nv[j] = Lv[j]; }
    }
}

extern "C" void kernel_launch(void* const* d_in, const int* in_sizes, int n_in,
                              void* d_out, int out_size, void* d_ws, size_t ws_size,
                              hipStream_t stream) {
    const float* I       = (const float*)d_in[0];
    const float* tau_m   = (const float*)d_in[1];
    const float* tau_s   = (const float*)d_in[2];
    const float* v_th    = (const float*)d_in[3];
    const float* v_reset = (const float*)d_in[4];
    float* out = (float*)d_out;

    if (ws_size >= WS_NEED) {
        int* flags = (int*)d_ws;
        conv_kernel<<<dim3(NROWS * CHK / WPB), dim3(256), 0, stream>>>(
            I, tau_m, tau_s, v_th, v_reset, out, flags);
        fixup_kernel<<<dim3(NROWS / WPB), dim3(256), 0, stream>>>(flags, out);
    } else {
        srm_kernel<<<dim3(NROWS / WPB), dim3(256), 0, stream>>>(
            I, tau_m, tau_s, v_th, v_reset, out);
    }
}

// Round 14
// 147.604 us; speedup vs baseline: 1.4932x; 1.0923x over previous
//
#include <hip/hip_runtime.h>

// SRM neuron: per-row 50-tap 'same' conv -> threshold -> refractory scan.
// B=4096 rows, T=16384.
// R13 = R12 with the 'same'-shift bug fixed: output t uses the window ending
//       at t+24 (reference: I_filt[t] = sum_j k[j] x[t+24-j]); R12 used the
//       window ending at t (spikes shifted by 24 -> absmax 1.0).
//       Window base is now off = t0 - 28; both row edges get guarded
//       zero-filled f4 loads (window reaches x[t+39] past the row end).
//   K1: per-lane bootstrap (50-step f64 Horner dot) + 15-step window
//       recurrence y' = A*y + x - A^50*lag. No cross-lane scan, no carry.
//       65536 independent waves. Numerics validated by R11 (absmax 0.0).
//   K0: 5 f64 constants + exact threshold (R8 lesson: no per-wave setup).
//   K2: validated fixup repairs refractory overlaps on flagged rows.
// Fallback: validated self-contained R7 kernel if ws too small.

#define TLEN   16384
#define NROWS  4096
#define KLEN   50
#define WPB    4        // waves per 256-thread block
#define SEGS   16       // segments per row
#define SEGLEN 1024     // elems per segment (64 lanes x 16)

// fixup / fallback geometry
#define FGRP  256
#define FNGRP 64
#define TILEW 336

// d_ws layout: double[0..4] = Ad, Bd, A50, B50, athrS; flags at byte 256.
#define WS_FLAGS_OFF 256
#define WS_NEED (WS_FLAGS_OFF + (size_t)NROWS * SEGS * sizeof(int))

typedef float f4 __attribute__((ext_vector_type(4)));

__device__ __forceinline__ float uniformf(float x) {
    return __int_as_float(__builtin_amdgcn_readfirstlane(__float_as_int(x)));
}

// compose: r[s] = then[first[s]]  (apply `first`, then `then`)
__device__ __forceinline__ int map_compose(int first, int then) {
    int r = 0;
#pragma unroll
    for (int s = 0; s < 4; ++s) {
        int a = (first >> (2 * s)) & 3;
        int b = (then >> (2 * a)) & 3;
        r |= b << (2 * s);
    }
    return r;
}

// Smallest float a with (v_reset + a/100.0f) >= v_th, via exact-predicate
// binary search over order-mapped float bits. cand == (acc >= athr) EXACTLY.
__device__ float solve_thresh(float v_reset, float v_th) {
    auto tokey = [](float f) {
        unsigned u = __float_as_uint(f);
        return (u & 0x80000000u) ? ~u : (u | 0x80000000u);
    };
    auto fromkey = [](unsigned k) {
        unsigned u = (k & 0x80000000u) ? (k & 0x7FFFFFFFu) : ~k;
        return __uint_as_float(u);
    };
    const float maxf = 3.402823466e38f;
    unsigned lo = tokey(-maxf), hi = tokey(maxf);
    if (!((v_reset + maxf / 100.0f) >= v_th))
        return __uint_as_float(0x7F800000u);  // pred never true -> +inf
    while (lo < hi) {
        unsigned mid = lo + ((hi - lo) >> 1);
        float a = fromkey(mid);
        if ((v_reset + a / 100.0f) >= v_th) hi = mid;
        else lo = mid + 1;
    }
    return fromkey(lo);
}

// ---------------- K0: f64 constants + exact threshold -> d_ws ----------------
__global__ __launch_bounds__(64)
void setup_kernel(const float* __restrict__ p_tau_m,
                  const float* __restrict__ p_tau_s,
                  const float* __restrict__ p_v_th,
                  const float* __restrict__ p_v_reset,
                  double* __restrict__ wsd)
{
    if (threadIdx.x != 0) return;
    const double tm = (double)p_tau_m[0];
    const double ts = (double)p_tau_s[0];
    const double Ad  = exp(-1.0 / tm);
    const double Bd  = exp(-1.0 / ts);
    const double A50 = exp(-50.0 / tm);
    const double B50 = exp(-50.0 / ts);
    // Unnormalized-tap sum S = sum_{t<50} (A^t - B^t); threshold on the
    // unnormalized window sum: cand <=> (ya - yb) >= athr * (S + 1e-10).
    const double S = (1.0 - A50) / (1.0 - Ad) - (1.0 - B50) / (1.0 - Bd);
    const float athr = solve_thresh(p_v_reset[0], p_v_th[0]);
    wsd[0] = Ad;
    wsd[1] = Bd;
    wsd[2] = A50;
    wsd[3] = B50;
    wsd[4] = (double)athr * (S + 1e-10);
}

// ---------------- K1: per-lane window recurrence -> spikes + flags ----------------
__global__ __launch_bounds__(256)
void conv_kernel(const float* __restrict__ I,
                 const double* __restrict__ wsd,
                 float* __restrict__ out,
                 int* __restrict__ flags)
{
    const int lane = threadIdx.x & 63;
    const int wid  = threadIdx.x >> 6;
    const int wg   = blockIdx.x * WPB + wid;   // 0 .. NROWS*SEGS-1
    const int row  = wg >> 4;
    const int seg  = wg & 15;

    // Wave-uniform f64 constants (scalar loads; no transcendentals here).
    const double Ad    = wsd[0];
    const double Bd    = wsd[1];
    const double A50   = wsd[2];
    const double B50   = wsd[3];
    const double athrS = wsd[4];

    const float* Irow = I + (size_t)row * TLEN;
    float* Orow = out + (size_t)row * TLEN;

    const int pos0 = seg * SEGLEN;
    const int t0   = pos0 + 16 * lane;   // lane's first output position
    // Output t uses window ending at t+24 spanning x[t-25 .. t+24].
    // Window for outputs t0..t0+15: x[t0-25 .. t0+39]. Aligned base:
    const int off  = t0 - 28;            // off % 4 == 0; WIN(m) = x[off+m]

    // ---- load window x[off .. off+67] (17 x f4; zeros outside the row) ----
    f4 wv[17];
    if (off >= 0 && off <= TLEN - 68) {
#pragma unroll
        for (int i = 0; i < 17; ++i)
            wv[i] = *(const f4*)(Irow + off + 4 * i);
    } else {
#pragma unroll
        for (int i = 0; i < 17; ++i) {
            const int idx = off + 4 * i;   // multiple of 4: f4 all-in or all-out
            wv[i] = (idx >= 0 && idx <= TLEN - 4)
                        ? *(const f4*)(Irow + idx)
                        : (f4){0.0f, 0.0f, 0.0f, 0.0f};
        }
    }
#define WIN(m) ((double)wv[(m) >> 2][(m) & 3])

    // ---- k=0 bootstrap: 50-step Horner dot, j = 49..0 ----
    // pa = sum_j A^j x[(t0+24) - j]  (window ending t0+24 -> output t0)
    double pa = 0.0, pb = 0.0;
#pragma unroll
    for (int j = 49; j >= 0; --j) {
        const double xx = WIN(52 - j);   // x[t0 + 24 - j]
        pa = fma(Ad, pa, xx);
        pb = fma(Bd, pb, xx);
    }

    int m16 = ((pa - pb) >= athrS) ? 1 : 0;

    // ---- k = 1..15: exact window recurrence (end position t0+24+k) ----
#pragma unroll
    for (int k = 1; k < 16; ++k) {
        const double xk = WIN(52 + k);   // x[t0 + 24 + k]
        const double lk = WIN(2 + k);    // x[(t0 + 24 + k) - 50]
        pa = fma(Ad, pa, fma(-A50, lk, xk));
        pb = fma(Bd, pb, fma(-B50, lk, xk));
        m16 |= ((pa - pb) >= athrS) ? (1 << k) : 0;
    }
#undef WIN

    if (t0 == 0) m16 &= ~1;   // spikes[0] forced 0 (loop starts at t=1)
    const int rowflag = m16;

    // ---- transpose to coalesced stores via shuffles (R10-validated) ----
    const int sh = 4 * (lane & 3);
#pragma unroll
    for (int j = 0; j < 4; ++j) {
        const int bits = __shfl(m16, (lane >> 2) + 16 * j, 64);
        f4 o0;
        o0.x = ((bits >> (sh + 0)) & 1) ? 1.0f : 0.0f;
        o0.y = ((bits >> (sh + 1)) & 1) ? 1.0f : 0.0f;
        o0.z = ((bits >> (sh + 2)) & 1) ? 1.0f : 0.0f;
        o0.w = ((bits >> (sh + 3)) & 1) ? 1.0f : 0.0f;
        __builtin_nontemporal_store(o0, (f4*)(Orow + pos0 + 4 * lane + 256 * j));
    }

    // Deterministic flag write for every wave-group (0 or 1).
    const unsigned long long anyb = __ballot(rowflag != 0);
    if (lane == 0) flags[wg] = (anyb != 0ULL) ? 1 : 0;
}

// ---------------- K2: repair flagged rows with exact refractory scan ----------------
__global__ __launch_bounds__(256)
void fixup_kernel(const int* __restrict__ flags,
                  float* __restrict__ out)
{
    const int lane = threadIdx.x & 63;
    const int wid  = threadIdx.x >> 6;
    const int row  = blockIdx.x * WPB + wid;

    const int* pf = flags + SEGS * row;
    int any = 0;
#pragma unroll
    for (int j = 0; j < SEGS; ++j) any |= pf[j];
    if (any == 0) return;  // wave-uniform

    float* Orow = out + (size_t)row * TLEN;
    int r0 = 0;

    for (int g = 0; g < FNGRP; ++g) {
        f4 o = *(const f4*)(Orow + g * FGRP + 4 * lane);
        int cand[4];
        cand[0] = (o.x != 0.0f);
        cand[1] = (o.y != 0.0f);
        cand[2] = (o.z != 0.0f);
        cand[3] = (o.w != 0.0f);

        const int cm = cand[0] | cand[1] | cand[2] | cand[3];
        const unsigned long long anyc = __ballot(cm != 0);
        if (anyc == 0ULL) { r0 = 0; continue; }   // zeros already correct

        int s0 = 0, s1 = 1, s2 = 2, s3 = 3;
#pragma unroll
        for (int k = 0; k < 4; ++k) {
            const int c3 = cand[k] ? 3 : 0;
            s0 = (s0 > 0) ? (s0 - 1) : c3;
            s1 = (s1 > 0) ? (s1 - 1) : c3;
            s2 = (s2 > 0) ? (s2 - 1) : c3;
            s3 = (s3 > 0) ? (s3 - 1) : c3;
        }
        int P = s0 | (s1 << 2) | (s2 << 4) | (s3 << 6);

#pragma unroll
        for (int d = 1; d < 64; d <<= 1) {
            const int prev = __shfl_up(P, d, 64);
            const int comp = map_compose(prev, P);
            P = (lane >= d) ? comp : P;
        }
        const int Pprev = __shfl_up(P, 1, 64);
        const int sin0  = (lane == 0) ? r0 : ((Pprev >> (2 * r0)) & 3);
        const int Pfull = __shfl(P, 63, 64);
        r0 = (Pfull >> (2 * r0)) & 3;

        int s = sin0;
        float sp[4];
#pragma unroll
        for (int k = 0; k < 4; ++k) {
            const int spike = (s == 0) & cand[k];
            sp[k] = spike ? 1.0f : 0.0f;
            s = (s > 0) ? (s - 1) : (cand[k] ? 3 : 0);
        }
        f4 o0; o0.x = sp[0]; o0.y = sp[1]; o0.z = sp[2]; o0.w = sp[3];
        *(f4*)(Orow + g * FGRP + 4 * lane) = o0;
    }
}

// ---------------- Fallback: validated R7 single kernel ----------------
__global__ __launch_bounds__(256)
void srm_kernel(const float* __restrict__ I,
                const float* __restrict__ p_tau_m,
                const float* __restrict__ p_tau_s,
                const float* __restrict__ p_v_th,
                const float* __restrict__ p_v_reset,
                float* __restrict__ out)
{
    __shared__ __align__(16) float tile[WPB][2][TILEW];

    const int lane = threadIdx.x & 63;
    const int wid  = threadIdx.x >> 6;
    const int row  = blockIdx.x * WPB + wid;

    const float tau_m   = p_tau_m[0];
    const float tau_s   = p_tau_s[0];
    const float v_th    = p_v_th[0];
    const float v_reset = p_v_reset[0];

    float ku[KLEN];
    float ksum = 0.0f;
#pragma unroll
    for (int t = 0; t < KLEN; ++t) {
        float ft = (float)t;
        float v = expf(-ft / tau_m) - expf(-ft / tau_s);
        ksum += v;
        ku[t] = uniformf(v);
    }
    const float kden = uniformf(ksum + 1e-10f);
    float kt[KLEN];
#pragma unroll
    for (int t = 0; t < KLEN; ++t) kt[t] = uniformf(ku[t] / kden);

    const float athr = uniformf(solve_thresh(v_reset, v_th));

    const float* Irow = I + (size_t)row * TLEN;
    float* Orow = out + (size_t)row * TLEN;

    float Cv[4], Nv[4], Lv[4];
    {
        f4 a = *(const f4*)(Irow + 0 * FGRP + 4 * lane);
        Cv[0] = a.x; Cv[1] = a.y; Cv[2] = a.z; Cv[3] = a.w;
        f4 c = *(const f4*)(Irow + 1 * FGRP + 4 * lane);
        Nv[0] = c.x; Nv[1] = c.y; Nv[2] = c.z; Nv[3] = c.w;
    }

    if (lane < 8) {
        f4 z = (f4){0.0f, 0.0f, 0.0f, 0.0f};
        *(f4*)&tile[wid][0][4 * lane] = z;
    }
    {
        f4 c; c.x = Cv[0]; c.y = Cv[1]; c.z = Cv[2]; c.w = Cv[3];
        *(f4*)&tile[wid][0][32 + 4 * lane] = c;
    }

    int r0 = 0;

    for (int g = 0; g < FNGRP; ++g) {
        const int cur = g & 1;
        const int nxt = cur ^ 1;

        if (g + 2 < FNGRP) {
            f4 a = *(const f4*)(Irow + (size_t)(g + 2) * FGRP + 4 * lane);
            Lv[0] = a.x; Lv[1] = a.y; Lv[2] = a.z; Lv[3] = a.w;
        } else {
            Lv[0] = Lv[1] = Lv[2] = Lv[3] = 0.0f;
        }

        f4 nv; nv.x = Nv[0]; nv.y = Nv[1]; nv.z = Nv[2]; nv.w = Nv[3];
        if (lane < 8)
            *(f4*)&tile[wid][cur][288 + 4 * lane] = nv;
        *(f4*)&tile[wid][nxt][32 + 4 * lane] = nv;
        if (lane >= 56) {
            f4 cv; cv.x = Cv[0]; cv.y = Cv[1]; cv.z = Cv[2]; cv.w = Cv[3];
            *(f4*)&tile[wid][nxt][4 * (lane - 56)] = cv;
        }

        f4 wv[15];
#pragma unroll
        for (int i = 0; i < 15; ++i)
            wv[i] = *(const f4*)&tile[wid][cur][4 * lane + 4 + 4 * i];
#define WIN(m) (wv[(m) >> 2][(m) & 3])

        float acc[4];
        acc[0] = acc[1] = acc[2] = acc[3] = 0.0f;
#pragma unroll
        for (int o = -25; o <= 27; ++o) {
            const float w = WIN(o + 28);
#pragma unroll
            for (int k = 0; k < 4; ++k) {
                const int jj = k + 24 - o;
                if (jj >= 0 && jj < KLEN)
                    acc[k] = fmaf(kt[jj], w, acc[k]);
            }
        }
#undef WIN

        const int tb = g * FGRP + 4 * lane;
        int cand[4];
#pragma unroll
        for (int k = 0; k < 4; ++k)
            cand[k] = (acc[k] >= athr) ? 1 : 0;
        cand[0] &= (tb != 0);

        const int cm = cand[0] | cand[1] | cand[2] | cand[3];
        const unsigned long long anyc = __ballot(cm != 0);

        f4 o0;
        if (anyc == 0ULL) {
            o0 = (f4){0.0f, 0.0f, 0.0f, 0.0f};
            r0 = 0;
        } else {
            int s0 = 0, s1 = 1, s2 = 2, s3 = 3;
#pragma unroll
            for (int k = 0; k < 4; ++k) {
                const int c3 = cand[k] ? 3 : 0;
                s0 = (s0 > 0) ? (s0 - 1) : c3;
                s1 = (s1 > 0) ? (s1 - 1) : c3;
                s2 = (s2 > 0) ? (s2 - 1) : c3;
                s3 = (s3 > 0) ? (s3 - 1) : c3;
            }
            int P = s0 | (s1 << 2) | (s2 << 4) | (s3 << 6);
#pragma unroll
            for (int d = 1; d < 64; d <<= 1) {
                const int prev = __shfl_up(P, d, 64);
                const int comp = map_compose(prev, P);
                P = (lane >= d) ? comp : P;
            }
            const int Pprev = __shfl_up(P, 1, 64);
            const int sin0  = (lane == 0) ? r0 : ((Pprev >> (2 * r0)) & 3);
            const int Pfull = __shfl(P, 63, 64);
            r0 = (Pfull >> (2 * r0)) & 3;

            int s = sin0;
            float sp[4];
#pragma unroll
            for (int k = 0; k < 4; ++k) {
                const int spike = (s == 0) & cand[k];
                sp[k] = spike ? 1.0f : 0.0f;
                s = (s > 0) ? (s - 1) : (cand[k] ? 3 : 0);
            }
            o0.x = sp[0]; o0.y = sp[1]; o0.z = sp[2]; o0.w = sp[3];
        }

        __builtin_nontemporal_store(o0, (f4*)(Orow + tb));

#pragma unroll
        for (int j = 0; j < 4; ++j) { Cv[j] = Nv[j]; Nv[j] = Lv[j]; }
    }
}

extern "C" void kernel_launch(void* const* d_in, const int* in_sizes, int n_in,
                              void* d_out, int out_size, void* d_ws, size_t ws_size,
                              hipStream_t stream) {
    const float* I       = (const float*)d_in[0];
    const float* tau_m   = (const float*)d_in[1];
    const float* tau_s   = (const float*)d_in[2];
    const float* v_th    = (const float*)d_in[3];
    const float* v_reset = (const float*)d_in[4];
    float* out = (float*)d_out;

    if (ws_size >= WS_NEED) {
        double* wsd = (double*)d_ws;
        int* flags  = (int*)((char*)d_ws + WS_FLAGS_OFF);
        setup_kernel<<<dim3(1), dim3(64), 0, stream>>>(
            tau_m, tau_s, v_th, v_reset, wsd);
        conv_kernel<<<dim3(NROWS * SEGS / WPB), dim3(256), 0, stream>>>(
            I, wsd, out, flags);
        fixup_kernel<<<dim3(NROWS / WPB), dim3(256), 0, stream>>>(flags, out);
    } else {
        srm_kernel<<<dim3(NROWS / WPB), dim3(256), 0, stream>>>(
            I, tau_m, tau_s, v_th, v_reset, out);
    }
}